// Round 1
// baseline (556.783 us; speedup 1.0000x reference)
//
#include <hip/hip_runtime.h>
#include <hip/hip_bf16.h>
#include <stdint.h>

#define HP 58
#define WP 64
#define CIN 256
#define COUT 256
#define HH 56
#define WW 56
#define IMG_STRIDE (HP*WP*CIN)   // 950272 elems per image
#define ROW_STRIDE (WP*CIN)      // 16384 elems per padded row
#define NPIX 200704.0            // 64*56*56

typedef __attribute__((ext_vector_type(8))) __bf16 bf16x8;
typedef __attribute__((ext_vector_type(4))) float f32x4;

#define GLDS(g, l) __builtin_amdgcn_global_load_lds( \
    (const __attribute__((address_space(1))) void*)(g), \
    (__attribute__((address_space(3))) void*)(l), 16, 0, 0)

// ---------- K1: per-(channel,image) partial sums in fp64 (deterministic) ----------
__global__ __launch_bounds__(256) void stats_partial(const float* __restrict__ x,
                                                     double* __restrict__ part) {
  int b = blockIdx.x;            // 256*64
  int c = b >> 6, n = b & 63;
  const float* p = x + (size_t)(n*CIN + c) * (HH*WW);
  double s = 0.0, s2 = 0.0;
  for (int i = threadIdx.x; i < HH*WW; i += 256) {
    double v = (double)p[i];
    s += v; s2 += v*v;
  }
  for (int off = 32; off > 0; off >>= 1) {
    s  += __shfl_down(s, off);
    s2 += __shfl_down(s2, off);
  }
  __shared__ double red[8];
  int wv = threadIdx.x >> 6, ln = threadIdx.x & 63;
  if (ln == 0) { red[wv*2] = s; red[wv*2+1] = s2; }
  __syncthreads();
  if (threadIdx.x == 0) {
    double ts = ((red[0]+red[2])+red[4])+red[6];
    double t2 = ((red[1]+red[3])+red[5])+red[7];
    part[(size_t)(c*64 + n)*2]     = ts;
    part[(size_t)(c*64 + n)*2 + 1] = t2;
  }
}

// ---------- K2: finalize per-channel {mean, gamma*inv_std, beta} in fp64 ----------
__global__ void stats_final(const double* __restrict__ part,
                            const float* __restrict__ gamma,
                            const float* __restrict__ beta,
                            double* __restrict__ prm) {
  int c = threadIdx.x;
  double s = 0.0, s2 = 0.0;
  for (int n = 0; n < 64; ++n) {
    s  += part[(size_t)(c*64+n)*2];
    s2 += part[(size_t)(c*64+n)*2 + 1];
  }
  double mean = s / NPIX;
  double var  = s2 / NPIX - mean*mean;
  double inv  = 1.0 / sqrt(var + 1e-5);
  prm[c*4+0] = mean;
  prm[c*4+1] = (double)gamma[c] * inv;
  prm[c*4+2] = (double)beta[c];
}

// ---------- K3: binarize + transpose to padded NHWC64 bf16 ----------
__global__ __launch_bounds__(256) void binarize(const float* __restrict__ x,
                                                const double* __restrict__ prm,
                                                uint16_t* __restrict__ xb) {
  int b = blockIdx.x;            // 64*58
  int n = b / HP, y = b % HP;
  uint16_t* orow = xb + (size_t)(n*HP + y) * ROW_STRIDE;
  if (y == 0 || y == HP-1) {     // zero padding rows
    int4 z = {0,0,0,0};
    int4* q = (int4*)orow;
    for (int i = threadIdx.x; i < ROW_STRIDE*2/16; i += 256) q[i] = z;
    return;
  }
  __shared__ uint16_t sbuf[CIN][58];   // pad 58 -> stride 29 dwords, conflict-free reads
  int h  = y - 1;
  int cl = threadIdx.x >> 6, wl = threadIdx.x & 63;
  for (int c0 = 0; c0 < CIN; c0 += 4) {
    int c = c0 + cl;
    if (wl < WW) {
      double xv = (double)x[((size_t)(n*CIN + c)*HH + h)*WW + wl];
      double v  = (xv - prm[c*4]) * prm[c*4+1] + prm[c*4+2];
      sbuf[c][wl] = v > 0.0 ? (uint16_t)0x3F80u : (v < 0.0 ? (uint16_t)0xBF80u : (uint16_t)0u);
    }
  }
  __syncthreads();
  int c = threadIdx.x;
  for (int xx = 0; xx < WP; ++xx) {
    uint16_t v = (xx >= 1 && xx <= WW) ? sbuf[c][xx-1] : (uint16_t)0;
    orow[xx*CIN + c] = v;
  }
}

// ---------- K4: repack W[co][ci][3][3] fp32 -> Wb[tap][co][ci] bf16 ----------
__global__ __launch_bounds__(256) void wrepack(const float* __restrict__ W,
                                               uint16_t* __restrict__ Wb) {
  int idx = blockIdx.x * 256 + threadIdx.x;   // < 9*256*256
  int ci = idx & 255, co = (idx >> 8) & 255, tap = idx >> 16;
  float v = W[(size_t)co*(CIN*9) + ci*9 + tap];
  __bf16 hb = (__bf16)v;
  Wb[idx] = __builtin_bit_cast(uint16_t, hb);
}

// ---------- K5: implicit-GEMM conv, m97 structure ----------
// GEMM: D[co][pos] = sum_k Wb[tap][co][ci] * xb[pos_base + pos*256 + ci]
// tile 128co x 128pos, BK=32, 4 waves (2x2), 16x16x32 bf16 MFMA
__global__ __launch_bounds__(256) void conv_gemm(const uint16_t* __restrict__ xb,
                                                 const uint16_t* __restrict__ Wb,
                                                 float* __restrict__ out) {
  int bid = blockIdx.x;
  int co0 = (bid & 1) * 128;
  int pt  = bid >> 1;                 // 0..1791
  int n   = pt / 28;
  int y0  = 1 + (pt % 28) * 2;        // two padded rows y0, y0+1

  __shared__ uint16_t ldsW[128][32];
  __shared__ uint16_t ldsX[128][32];

  int tid = threadIdx.x;
  int wv = tid >> 6, ln = tid & 63;
  int wco = wv >> 1, wpos = wv & 1;

  f32x4 acc[4][4] = {};

  long nbase = (long)n * IMG_STRIDE;
  int srow = tid >> 2;                // 0..63
  int scol = (tid & 3) * 8;

  for (int tap = 0; tap < 9; ++tap) {
    int kh = tap / 3, kw = tap - kh*3;
    long xflat = nbase + (long)(y0 - 1 + kh) * ROW_STRIDE + (long)(kw - 1) * CIN;
    const uint16_t* wt = Wb + tap*(COUT*CIN) + co0*CIN;
    for (int cs = 0; cs < 8; ++cs) {
      int ci0 = cs * 32;
      __syncthreads();   // previous iter's ds_reads done before overwrite
      const uint16_t* wg = wt + srow*CIN + ci0 + scol;
      const uint16_t* xg = xb + xflat + (long)srow*CIN + ci0 + scol;
      GLDS(wg,            (char*)ldsW + wv*1024);
      GLDS(wg + 64*CIN,   (char*)ldsW + 4096 + wv*1024);
      GLDS(xg,            (char*)ldsX + wv*1024);
      GLDS(xg + 64*CIN,   (char*)ldsX + 4096 + wv*1024);
      __syncthreads();   // compiler drains vmcnt(0) here

      const char* lwb = (const char*)ldsW + wco*4096  + (ln & 15)*64 + (ln >> 4)*16;
      const char* lxb = (const char*)ldsX + wpos*4096 + (ln & 15)*64 + (ln >> 4)*16;
      bf16x8 af[4], bfr[4];
      #pragma unroll
      for (int i = 0; i < 4; ++i) {
        af[i]  = *(const bf16x8*)(lwb + i*1024);
        bfr[i] = *(const bf16x8*)(lxb + i*1024);
      }
      #pragma unroll
      for (int mi = 0; mi < 4; ++mi)
        #pragma unroll
        for (int ni = 0; ni < 4; ++ni)
          acc[mi][ni] = __builtin_amdgcn_mfma_f32_16x16x32_bf16(af[mi], bfr[ni], acc[mi][ni], 0, 0, 0);
    }
  }

  // epilogue: D[row=(ln>>4)*4+r (co), col=ln&15 (pos)], ReLU, NCHW store
  int h_  = y0 - 1 + wpos;
  int coB = co0 + wco*64 + (ln >> 4)*4;
  int xxB = (ln & 15);
  #pragma unroll
  for (int ni = 0; ni < 4; ++ni) {
    int xx = xxB + ni*16;
    if (xx < 1 || xx > WW) continue;
    long obase = (long)n*COUT*(HH*WW) + h_*WW + (xx-1);
    #pragma unroll
    for (int mi = 0; mi < 4; ++mi) {
      int co = coB + mi*16;
      #pragma unroll
      for (int r = 0; r < 4; ++r)
        out[obase + (long)(co + r)*(HH*WW)] = fmaxf(acc[mi][ni][r], 0.0f);
    }
  }
}

extern "C" void kernel_launch(void* const* d_in, const int* in_sizes, int n_in,
                              void* d_out, int out_size, void* d_ws, size_t ws_size,
                              hipStream_t stream) {
  const float* x     = (const float*)d_in[0];
  const float* gamma = (const float*)d_in[1];
  const float* beta  = (const float*)d_in[2];
  const float* W     = (const float*)d_in[3];
  float* out = (float*)d_out;

  char* ws = (char*)d_ws;
  // layout: partials [262144 B] | params [8192 B] | Wb [1179648 B] | guard | xb | guard
  double*   part = (double*)ws;                        // 16384 double2
  double*   prm  = (double*)(ws + 262144);             // 256 * 4 doubles
  uint16_t* Wb   = (uint16_t*)(ws + 270336);           // 9*256*256 bf16
  uint16_t* xb   = (uint16_t*)(ws + 1451008);          // 512B pre-guard before this
  // xb data: 64*58*64*256 elems = 121,634,816 B ; 512B post-guard ; total ~123.1 MB

  hipLaunchKernelGGL(stats_partial, dim3(256*64), dim3(256), 0, stream, x, part);
  hipLaunchKernelGGL(stats_final,   dim3(1),      dim3(256), 0, stream, part, gamma, beta, prm);
  hipLaunchKernelGGL(binarize,      dim3(64*HP),  dim3(256), 0, stream, x, prm, xb);
  hipLaunchKernelGGL(wrepack,       dim3(9*256),  dim3(256), 0, stream, W, Wb);
  hipLaunchKernelGGL(conv_gemm,     dim3(2*64*28),dim3(256), 0, stream, xb, Wb, out);
}

// Round 2
// 499.437 us; speedup vs baseline: 1.1148x; 1.1148x over previous
//
#include <hip/hip_runtime.h>
#include <hip/hip_bf16.h>
#include <stdint.h>

#define HP 58
#define WP 64
#define CIN 256
#define COUT 256
#define HH 56
#define WW 56
#define IMG_STRIDE (HP*WP*CIN)   // 950272 elems per image
#define ROW_STRIDE (WP*CIN)      // 16384 elems per padded row
#define NPIX 200704.0            // 64*56*56

typedef __attribute__((ext_vector_type(8))) __bf16 bf16x8;
typedef __attribute__((ext_vector_type(4))) float f32x4;

#define GLDS(g, l) __builtin_amdgcn_global_load_lds( \
    (const __attribute__((address_space(1))) void*)(g), \
    (__attribute__((address_space(3))) void*)(l), 16, 0, 0)

// ---------- K1: per-(channel,image) partial sums in fp64 (deterministic) ----------
__global__ __launch_bounds__(256) void stats_partial(const float* __restrict__ x,
                                                     double* __restrict__ part) {
  int b = blockIdx.x;            // 256*64
  int c = b >> 6, n = b & 63;
  const float4* p = (const float4*)(x + (size_t)(n*CIN + c) * (HH*WW));
  double s = 0.0, s2 = 0.0;
  for (int i = threadIdx.x; i < 784; i += 256) {   // 784 float4 = 3136 floats
    float4 v = p[i];
    double a0 = v.x, a1 = v.y, a2 = v.z, a3 = v.w;
    s  += (a0 + a1) + (a2 + a3);
    s2 += (a0*a0 + a1*a1) + (a2*a2 + a3*a3);
  }
  for (int off = 32; off > 0; off >>= 1) {
    s  += __shfl_down(s, off);
    s2 += __shfl_down(s2, off);
  }
  __shared__ double red[8];
  int wv = threadIdx.x >> 6, ln = threadIdx.x & 63;
  if (ln == 0) { red[wv*2] = s; red[wv*2+1] = s2; }
  __syncthreads();
  if (threadIdx.x == 0) {
    double ts = ((red[0]+red[2])+red[4])+red[6];
    double t2 = ((red[1]+red[3])+red[5])+red[7];
    part[(size_t)(c*64 + n)*2]     = ts;
    part[(size_t)(c*64 + n)*2 + 1] = t2;
  }
}

// ---------- K2: finalize per-channel {mean, gamma*inv_std, beta} in fp64 ----------
__global__ void stats_final(const double* __restrict__ part,
                            const float* __restrict__ gamma,
                            const float* __restrict__ beta,
                            double* __restrict__ prm) {
  int c = threadIdx.x;
  double s = 0.0, s2 = 0.0;
  for (int n = 0; n < 64; ++n) {
    s  += part[(size_t)(c*64+n)*2];
    s2 += part[(size_t)(c*64+n)*2 + 1];
  }
  double mean = s / NPIX;
  double var  = s2 / NPIX - mean*mean;
  double inv  = 1.0 / sqrt(var + 1e-5);
  prm[c*4+0] = mean;
  prm[c*4+1] = (double)gamma[c] * inv;
  prm[c*4+2] = (double)beta[c];
}

// ---------- K3: binarize + transpose to padded NHWC64 bf16 ----------
__global__ __launch_bounds__(256) void binarize(const float* __restrict__ x,
                                                const double* __restrict__ prm,
                                                uint16_t* __restrict__ xb) {
  int b = blockIdx.x;            // 64*58
  int n = b / HP, y = b % HP;
  uint16_t* orow = xb + (size_t)(n*HP + y) * ROW_STRIDE;
  if (y == 0 || y == HP-1) {     // zero padding rows
    int4 z = {0,0,0,0};
    int4* q = (int4*)orow;
    for (int i = threadIdx.x; i < ROW_STRIDE*2/16; i += 256) q[i] = z;
    return;
  }
  __shared__ uint16_t sbuf[WW][CIN+2];   // stride 516B = 129 dwords (odd) -> conflict-free
  int h  = y - 1;
  int cl = threadIdx.x >> 6, wl = threadIdx.x & 63;
  for (int c0 = 0; c0 < CIN; c0 += 4) {
    int c = c0 + cl;
    if (wl < WW) {
      double xv = (double)x[((size_t)(n*CIN + c)*HH + h)*WW + wl];
      double v  = (xv - prm[c*4]) * prm[c*4+1] + prm[c*4+2];
      sbuf[wl][c] = v > 0.0 ? (uint16_t)0x3F80u : (v < 0.0 ? (uint16_t)0xBF80u : (uint16_t)0u);
    }
  }
  __syncthreads();
  // write phase: 2 padded cols at a time, uint32 (2 channels) per thread, fully coalesced
  int xh = threadIdx.x >> 7, cp = threadIdx.x & 127;
  uint32_t* orow32 = (uint32_t*)orow;
  for (int xx0 = 0; xx0 < WP; xx0 += 2) {
    int xx = xx0 + xh;
    uint32_t v = 0;
    if (xx >= 1 && xx <= WW) v = *(const uint32_t*)&sbuf[xx-1][cp*2];
    orow32[xx*128 + cp] = v;
  }
}

// ---------- K4: repack W[co][ci][3][3] fp32 -> Wb[tap][co][ci] bf16 ----------
__global__ __launch_bounds__(256) void wrepack(const float* __restrict__ W,
                                               uint16_t* __restrict__ Wb) {
  int idx = blockIdx.x * 256 + threadIdx.x;   // < 9*256*256
  int ci = idx & 255, co = (idx >> 8) & 255, tap = idx >> 16;
  float v = W[(size_t)co*(CIN*9) + ci*9 + tap];
  __bf16 hb = (__bf16)v;
  Wb[idx] = __builtin_bit_cast(uint16_t, hb);
}

// ---------- K5: implicit-GEMM conv, 256x256 8-wave m201-style schedule ----------
// D[co][pos] = sum_k Wb[tap][co][ci] * X[pos][ci],  K = 9 taps x 256 ci = 36 steps of 64.
// LDS 128 KiB: A/B x 2 dbuf x 2 halves(128 rows x 64 K x 2B, st-swizzled).
// 8 waves: wm=wid>>2 (co half), wn=wid&3 (64-pos row). acc[8][4] f32x4.
// Per K-step, 4 phases x {12|8|4|8 ds_read_b128, stage, s_barrier, lgkmcnt(0), 16 MFMA, s_barrier}.
// Region schedule (buf d = s&1):  A halves last read ph4 -> staged for s+2 at (s+1).ph1/ph2;
// B halves last read ph3 -> staged for s+2 at s.ph4 (both). vmcnt(4) once per step at ph4
// completes everything through A1(s+1), leaving the 4 B(s+2) loads in flight.
__global__ __launch_bounds__(512, 2) void conv_gemm(const uint16_t* __restrict__ xb,
                                                    const uint16_t* __restrict__ Wb,
                                                    float* __restrict__ out) {
  extern __shared__ char smem[];
  int bid = blockIdx.x;
  int swz = (bid & 7) * 112 + (bid >> 3);    // XCD-aware, bijective (896 % 8 == 0)
  int n_img = swz / 14, rg = swz - n_img * 14;
  int y0 = 1 + rg * 4;                       // 4 padded rows y0..y0+3

  int tid = threadIdx.x;
  int ln = tid & 63, wid = tid >> 6;
  int wm = wid >> 2, wn = wid & 3;

  // staging thread map: row = t>>3 (0..63 per issue), src col pre-swizzled (inverse of read swz)
  int srowT = tid >> 3;
  int scol8 = ((tid & 7) ^ (srowT & 7)) * 8;

  size_t xoff = (size_t)n_img * IMG_STRIDE + (size_t)(y0 - 1) * ROW_STRIDE;

  auto STAGE_A = [&](int step, int h) {      // one 16KB half-tile of W
    int sc = step < 36 ? step : 35;          // tail: clamp SOURCE only (dest parity unclamped)
    int tap = sc >> 2, ci0 = (sc & 3) << 6;
    const uint16_t* src = Wb + tap * (COUT*CIN) + ci0 + (size_t)(h*128 + srowT) * CIN + scol8;
    char* dst = smem + (((step & 1) * 2 + h) << 14) + tid * 16;
    GLDS(src, dst);
    GLDS(src + 64*CIN, dst + 8192);
  };
  auto STAGE_B = [&](int step, int h) {      // one 16KB half-tile of X
    int sc = step < 36 ? step : 35;
    int tap = sc >> 2, ci0 = (sc & 3) << 6;
    int kh = tap / 3, kw = tap - kh * 3;
    const uint16_t* src = xb + xoff + (long)kh * ROW_STRIDE + (long)(kw - 1) * CIN + ci0
                           + (size_t)(h*128 + srowT) * CIN + scol8;
    char* dst = smem + 65536 + (((step & 1) * 2 + h) << 14) + tid * 16;
    GLDS(src, dst);
    GLDS(src + 64*CIN, dst + 8192);
  };

  f32x4 acc[8][4] = {};

  // prologue: step0 all 4 half-tiles (8 loads), then B(1) (4 loads); wait first 8
  STAGE_A(0,0); STAGE_A(0,1); STAGE_B(0,0); STAGE_B(0,1);
  STAGE_B(1,0); STAGE_B(1,1);
  asm volatile("s_waitcnt vmcnt(4)" ::: "memory");
  __builtin_amdgcn_s_barrier();

  int rowbase = (ln & 15) * 128;
  int swzl = (ln & 7) << 4;
  int col0 = (((ln >> 4) << 4)) ^ swzl;        // kk=0 fragment col (swizzled)
  int col1 = (64 | ((ln >> 4) << 4)) ^ swzl;   // kk=1

  #pragma unroll 2
  for (int s = 0; s < 36; ++s) {
    int d = s & 1;
    const char* Ab = smem + ((d*2 + wm) << 14) + rowbase;
    const char* Bb = smem + 65536 + ((d*2 + (wn>>1)) << 14) + (wn & 1) * 8192 + rowbase;

    bf16x8 a0[4][2], a1[4][2], b0[2][2], b1[2][2];

    // ---- phase 1: read a[m0-3], b[n0-1]; stage A0(s+1); MFMA m0-3 x n0-1
    #pragma unroll
    for (int m = 0; m < 4; ++m) {
      a0[m][0] = *(const bf16x8*)(Ab + m*2048 + col0);
      a0[m][1] = *(const bf16x8*)(Ab + m*2048 + col1);
    }
    #pragma unroll
    for (int nn = 0; nn < 2; ++nn) {
      b0[nn][0] = *(const bf16x8*)(Bb + nn*2048 + col0);
      b0[nn][1] = *(const bf16x8*)(Bb + nn*2048 + col1);
    }
    STAGE_A(s+1, 0);
    __builtin_amdgcn_s_barrier();
    asm volatile("s_waitcnt lgkmcnt(0)" ::: "memory");
    __builtin_amdgcn_s_setprio(1);
    #pragma unroll
    for (int m = 0; m < 4; ++m)
      #pragma unroll
      for (int nn = 0; nn < 2; ++nn) {
        acc[m][nn] = __builtin_amdgcn_mfma_f32_16x16x32_bf16(a0[m][0], b0[nn][0], acc[m][nn], 0,0,0);
        acc[m][nn] = __builtin_amdgcn_mfma_f32_16x16x32_bf16(a0[m][1], b0[nn][1], acc[m][nn], 0,0,0);
      }
    __builtin_amdgcn_s_setprio(0);
    __builtin_amdgcn_s_barrier();

    // ---- phase 2: read a[m4-7]; stage A1(s+1); MFMA m4-7 x n0-1
    #pragma unroll
    for (int m = 0; m < 4; ++m) {
      a1[m][0] = *(const bf16x8*)(Ab + 8192 + m*2048 + col0);
      a1[m][1] = *(const bf16x8*)(Ab + 8192 + m*2048 + col1);
    }
    STAGE_A(s+1, 1);
    __builtin_amdgcn_s_barrier();
    asm volatile("s_waitcnt lgkmcnt(0)" ::: "memory");
    __builtin_amdgcn_s_setprio(1);
    #pragma unroll
    for (int m = 0; m < 4; ++m)
      #pragma unroll
      for (int nn = 0; nn < 2; ++nn) {
        acc[m+4][nn] = __builtin_amdgcn_mfma_f32_16x16x32_bf16(a1[m][0], b0[nn][0], acc[m+4][nn], 0,0,0);
        acc[m+4][nn] = __builtin_amdgcn_mfma_f32_16x16x32_bf16(a1[m][1], b0[nn][1], acc[m+4][nn], 0,0,0);
      }
    __builtin_amdgcn_s_setprio(0);
    __builtin_amdgcn_s_barrier();

    // ---- phase 3: read b[n2-3]; no stage; MFMA m4-7 x n2-3 (a1 live)
    #pragma unroll
    for (int nn = 0; nn < 2; ++nn) {
      b1[nn][0] = *(const bf16x8*)(Bb + 4096 + nn*2048 + col0);
      b1[nn][1] = *(const bf16x8*)(Bb + 4096 + nn*2048 + col1);
    }
    __builtin_amdgcn_s_barrier();
    asm volatile("s_waitcnt lgkmcnt(0)" ::: "memory");
    __builtin_amdgcn_s_setprio(1);
    #pragma unroll
    for (int m = 0; m < 4; ++m)
      #pragma unroll
      for (int nn = 0; nn < 2; ++nn) {
        acc[m+4][nn+2] = __builtin_amdgcn_mfma_f32_16x16x32_bf16(a1[m][0], b1[nn][0], acc[m+4][nn+2], 0,0,0);
        acc[m+4][nn+2] = __builtin_amdgcn_mfma_f32_16x16x32_bf16(a1[m][1], b1[nn][1], acc[m+4][nn+2], 0,0,0);
      }
    __builtin_amdgcn_s_setprio(0);
    __builtin_amdgcn_s_barrier();

    // ---- phase 4: re-read a[m0-3]; stage B0(s+2)+B1(s+2); vmcnt(4); MFMA m0-3 x n2-3
    #pragma unroll
    for (int m = 0; m < 4; ++m) {
      a0[m][0] = *(const bf16x8*)(Ab + m*2048 + col0);
      a0[m][1] = *(const bf16x8*)(Ab + m*2048 + col1);
    }
    STAGE_B(s+2, 0);
    STAGE_B(s+2, 1);
    __builtin_amdgcn_s_barrier();
    asm volatile("s_waitcnt vmcnt(4) lgkmcnt(0)" ::: "memory");
    __builtin_amdgcn_s_setprio(1);
    #pragma unroll
    for (int m = 0; m < 4; ++m)
      #pragma unroll
      for (int nn = 0; nn < 2; ++nn) {
        acc[m][nn+2] = __builtin_amdgcn_mfma_f32_16x16x32_bf16(a0[m][0], b1[nn][0], acc[m][nn+2], 0,0,0);
        acc[m][nn+2] = __builtin_amdgcn_mfma_f32_16x16x32_bf16(a0[m][1], b1[nn][1], acc[m][nn+2], 0,0,0);
      }
    __builtin_amdgcn_s_setprio(0);
    __builtin_amdgcn_s_barrier();
  }

  // epilogue: co = wm*128 + m*16 + (ln>>4)*4 + r ; pos = wn*64 + nn*16 + (ln&15)
  int coB = wm*128 + (ln >> 4) * 4;
  int y = y0 + wn;
  size_t obase0 = (size_t)n_img * COUT * (HH*WW) + (size_t)(y - 1) * WW;
  #pragma unroll
  for (int nn = 0; nn < 4; ++nn) {
    int xx = nn*16 + (ln & 15);
    if (xx < 1 || xx > WW) continue;
    size_t ob = obase0 + (xx - 1);
    #pragma unroll
    for (int m = 0; m < 8; ++m) {
      int co = coB + m*16;
      #pragma unroll
      for (int r = 0; r < 4; ++r)
        out[ob + (size_t)(co + r) * (HH*WW)] = fmaxf(acc[m][nn][r], 0.0f);
    }
  }
}

extern "C" void kernel_launch(void* const* d_in, const int* in_sizes, int n_in,
                              void* d_out, int out_size, void* d_ws, size_t ws_size,
                              hipStream_t stream) {
  const float* x     = (const float*)d_in[0];
  const float* gamma = (const float*)d_in[1];
  const float* beta  = (const float*)d_in[2];
  const float* W     = (const float*)d_in[3];
  float* out = (float*)d_out;

  char* ws = (char*)d_ws;
  // layout: partials [262144 B] | params [8192 B] | Wb [1179648 B] | guard | xb | guard
  double*   part = (double*)ws;                        // 16384 double2
  double*   prm  = (double*)(ws + 262144);             // 256 * 4 doubles
  uint16_t* Wb   = (uint16_t*)(ws + 270336);           // 9*256*256 bf16
  uint16_t* xb   = (uint16_t*)(ws + 1451008);          // 512B+ pre-guard before this
  // xb data: 64*58*64*256 elems = 121,634,816 B ; 512B post-guard ; total ~123.1 MB

  (void)hipFuncSetAttribute((const void*)conv_gemm,
                            hipFuncAttributeMaxDynamicSharedMemorySize, 131072);

  hipLaunchKernelGGL(stats_partial, dim3(256*64), dim3(256), 0, stream, x, part);
  hipLaunchKernelGGL(stats_final,   dim3(1),      dim3(256), 0, stream, part, gamma, beta, prm);
  hipLaunchKernelGGL(binarize,      dim3(64*HP),  dim3(256), 0, stream, x, prm, xb);
  hipLaunchKernelGGL(wrepack,       dim3(9*256),  dim3(256), 0, stream, W, Wb);
  hipLaunchKernelGGL(conv_gemm,     dim3(896),    dim3(512), 131072, stream, xb, Wb, out);
}

// Round 3
// 377.397 us; speedup vs baseline: 1.4753x; 1.3234x over previous
//
#include <hip/hip_runtime.h>
#include <hip/hip_bf16.h>
#include <stdint.h>

#define HP 58
#define WP 64
#define CIN 256
#define COUT 256
#define HH 56
#define WW 56
#define IMG_STRIDE (HP*WP*CIN)   // bytes per image in xb (i8): 950272
#define ROW_STRIDE (WP*CIN)      // bytes per padded row in xb: 16384
#define NPIX 200704.0            // 64*56*56

typedef __attribute__((ext_vector_type(4))) int i32x4;

#define GLDS(g, l) __builtin_amdgcn_global_load_lds( \
    (const __attribute__((address_space(1))) void*)(g), \
    (__attribute__((address_space(3))) void*)(l), 16, 0, 0)

// ---------- K1: per-(channel,image) partial sums in fp64 (deterministic) ----------
__global__ __launch_bounds__(256) void stats_partial(const float* __restrict__ x,
                                                     double* __restrict__ part) {
  int b = blockIdx.x;            // 256*64
  int c = b >> 6, n = b & 63;
  const float4* p = (const float4*)(x + (size_t)(n*CIN + c) * (HH*WW));
  double s = 0.0, s2 = 0.0;
  for (int i = threadIdx.x; i < 784; i += 256) {   // 784 float4 = 3136 floats
    float4 v = p[i];
    double a0 = v.x, a1 = v.y, a2 = v.z, a3 = v.w;
    s  += (a0 + a1) + (a2 + a3);
    s2 += (a0*a0 + a1*a1) + (a2*a2 + a3*a3);
  }
  for (int off = 32; off > 0; off >>= 1) {
    s  += __shfl_down(s, off);
    s2 += __shfl_down(s2, off);
  }
  __shared__ double red[8];
  int wv = threadIdx.x >> 6, ln = threadIdx.x & 63;
  if (ln == 0) { red[wv*2] = s; red[wv*2+1] = s2; }
  __syncthreads();
  if (threadIdx.x == 0) {
    double ts = ((red[0]+red[2])+red[4])+red[6];
    double t2 = ((red[1]+red[3])+red[5])+red[7];
    part[(size_t)(c*64 + n)*2]     = ts;
    part[(size_t)(c*64 + n)*2 + 1] = t2;
  }
}

// ---------- K2: finalize per-channel {mean, gamma*inv_std, beta} in fp64 ----------
__global__ void stats_final(const double* __restrict__ part,
                            const float* __restrict__ gamma,
                            const float* __restrict__ beta,
                            double* __restrict__ prm) {
  int c = threadIdx.x;
  double s = 0.0, s2 = 0.0;
  for (int n = 0; n < 64; ++n) {
    s  += part[(size_t)(c*64+n)*2];
    s2 += part[(size_t)(c*64+n)*2 + 1];
  }
  double mean = s / NPIX;
  double var  = s2 / NPIX - mean*mean;
  double inv  = 1.0 / sqrt(var + 1e-5);
  prm[c*4+0] = mean;
  prm[c*4+1] = (double)gamma[c] * inv;
  prm[c*4+2] = (double)beta[c];
}

// ---------- K3: binarize + transpose to padded NHWC64 int8 ----------
__global__ __launch_bounds__(256) void binarize(const float* __restrict__ x,
                                                const double* __restrict__ prm,
                                                int8_t* __restrict__ xb) {
  int b = blockIdx.x;            // 64*58
  int n = b / HP, y = b % HP;
  int8_t* orow = xb + (size_t)(n*HP + y) * ROW_STRIDE;
  if (y == 0 || y == HP-1) {     // zero padding rows: 16384 B
    int4 z = {0,0,0,0};
    int4* q = (int4*)orow;
    for (int i = threadIdx.x; i < ROW_STRIDE/16; i += 256) q[i] = z;
    return;
  }
  __shared__ char sbuf[WW][260];   // 260 = 65 dwords (odd) -> conflict-free both phases
  int h  = y - 1;
  int cl = threadIdx.x >> 6, wl = threadIdx.x & 63;
  for (int c0 = 0; c0 < CIN; c0 += 4) {
    int c = c0 + cl;
    if (wl < WW) {
      double xv = (double)x[((size_t)(n*CIN + c)*HH + h)*WW + wl];
      double v  = (xv - prm[c*4]) * prm[c*4+1] + prm[c*4+2];
      sbuf[wl][c] = v > 0.0 ? (int8_t)1 : (v < 0.0 ? (int8_t)-1 : (int8_t)0);
    }
  }
  __syncthreads();
  // write phase: 4 padded cols per iter, uint32 (4 channels) per thread, coalesced
  int xh = threadIdx.x >> 6, cq = threadIdx.x & 63;
  uint32_t* orow32 = (uint32_t*)orow;
  for (int xx0 = 0; xx0 < WP; xx0 += 4) {
    int xx = xx0 + xh;
    uint32_t v = 0;
    if (xx >= 1 && xx <= WW) v = *(const uint32_t*)&sbuf[xx-1][cq*4];
    orow32[xx*64 + cq] = v;
  }
}

// ---------- K4: quantize W[co][ci][3][3] fp32 -> Wb[tap][co][ci] i8, per-co scale ----------
__global__ __launch_bounds__(256) void wrepack(const float* __restrict__ W,
                                               int8_t* __restrict__ Wb,
                                               float* __restrict__ invs) {
  int co = blockIdx.x, ci = threadIdx.x;
  float w[9]; float mx = 0.f;
  const float* p = W + (size_t)co*(CIN*9) + ci*9;
  #pragma unroll
  for (int t = 0; t < 9; ++t) { w[t] = p[t]; mx = fmaxf(mx, fabsf(w[t])); }
  for (int off = 32; off > 0; off >>= 1) mx = fmaxf(mx, __shfl_xor(mx, off));
  __shared__ float sm[4];
  if ((threadIdx.x & 63) == 0) sm[threadIdx.x >> 6] = mx;
  __syncthreads();
  mx = fmaxf(fmaxf(sm[0], sm[1]), fmaxf(sm[2], sm[3]));
  float s = mx > 0.f ? 127.f / mx : 0.f;
  #pragma unroll
  for (int t = 0; t < 9; ++t) {
    int q = (int)lrintf(w[t] * s);
    q = q > 127 ? 127 : (q < -127 ? -127 : q);
    Wb[t*(COUT*CIN) + co*CIN + ci] = (int8_t)q;
  }
  if (threadIdx.x == 0) invs[co] = mx / 127.f;
}

// ---------- K5: implicit-GEMM conv, int8, 256co x 256pos, BK=128, 18 K-steps ----------
// D[co][pos] = sum Wb[tap][co][ci]*X[pos][ci], K = 9 taps x 256 ci; step = (tap, 128-ci-half).
// LDS 128 KiB: A/B x 2 dbuf x 2 halves (128 rows x 128 B, XOR-swizzled (row&7)<<4).
// 8 waves (wm 2 x wn 4); per step/wave: 64 mfma_i32_16x16x64_i8, 24 ds_read_b128 (no re-reads).
// Phases: ph1 {a0,b0; stage A0(s+1)} ph2 {b1; A1(s+1)} ph3 {a1; B0(s+2)} ph4 {-; B1(s+2); vmcnt(4)}.
__global__ __launch_bounds__(512, 2) void conv_gemm(const int8_t* __restrict__ xb,
                                                    const int8_t* __restrict__ Wb,
                                                    const float* __restrict__ invs,
                                                    float* __restrict__ out) {
  extern __shared__ char smem[];
  int bid = blockIdx.x;
  int swz = (bid & 7) * 112 + (bid >> 3);    // XCD-aware, bijective (896 % 8 == 0)
  int n_img = swz / 14, rg = swz - n_img * 14;
  int y0 = 1 + rg * 4;                       // 4 padded rows y0..y0+3

  int tid = threadIdx.x;
  int ln = tid & 63, wid = tid >> 6;
  int wm = wid >> 2, wn = wid & 3;

  int srowT = tid >> 3;                        // 0..63 rows per GLDS issue
  int scolB = ((tid & 7) ^ (srowT & 7)) * 16;  // pre-swizzled source col (bytes)

  size_t xoff = (size_t)n_img * IMG_STRIDE + (size_t)(y0 - 1) * ROW_STRIDE;

  auto STAGE_A = [&](int step, int h) {        // one 16KB half-tile of W
    int sc = step < 18 ? step : 17;            // tail: clamp SOURCE only
    int tap = sc >> 1, ci0 = (sc & 1) << 7;
    const int8_t* src = Wb + tap*(COUT*CIN) + (size_t)(h*128 + srowT)*CIN + ci0 + scolB;
    char* dst = smem + (((step & 1) * 2 + h) << 14) + tid * 16;
    GLDS(src, dst);
    GLDS(src + 64*CIN, dst + 8192);
  };
  auto STAGE_B = [&](int step, int h) {        // one 16KB half-tile of X
    int sc = step < 18 ? step : 17;
    int tap = sc >> 1, ci0 = (sc & 1) << 7;
    int kh = tap / 3, kw = tap - kh*3;
    const int8_t* src = xb + xoff + (long)kh * ROW_STRIDE + (long)(kw - 1) * CIN + ci0
                           + (size_t)(h*128 + srowT) * CIN + scolB;
    char* dst = smem + 65536 + (((step & 1) * 2 + h) << 14) + tid * 16;
    GLDS(src, dst);
    GLDS(src + 64*CIN, dst + 8192);
  };

  i32x4 acc[8][4] = {};

  // prologue: step0 all 4 half-tiles, then B(1); drain step0's 8 loads
  STAGE_A(0,0); STAGE_A(0,1); STAGE_B(0,0); STAGE_B(0,1);
  STAGE_B(1,0); STAGE_B(1,1);
  asm volatile("s_waitcnt vmcnt(4)" ::: "memory");
  __builtin_amdgcn_s_barrier();

  int rowbase = (ln & 15) * 128;
  int col0 = (((ln >> 4) << 4)) ^ ((ln & 7) << 4);   // kk=0 fragment col (swizzled)
  int col1 = col0 ^ 64;                              // kk=1

  #pragma unroll 1
  for (int s = 0; s < 18; ++s) {
    int d = s & 1;
    const char* Ab = smem + ((d*2 + wm) << 14) + rowbase;
    const char* Bb = smem + 65536 + ((d*2 + (wn>>1)) << 14) + (wn & 1) * 8192 + rowbase;

    i32x4 a0[4][2], a1[4][2], b0[2][2], b1[2][2];

    // ---- phase 1: read a0(m0-3), b0(n0-1); stage A0(s+1); MFMA m0-3 x n0-1
    #pragma unroll
    for (int m = 0; m < 4; ++m) {
      a0[m][0] = *(const i32x4*)(Ab + m*2048 + col0);
      a0[m][1] = *(const i32x4*)(Ab + m*2048 + col1);
    }
    #pragma unroll
    for (int nn = 0; nn < 2; ++nn) {
      b0[nn][0] = *(const i32x4*)(Bb + nn*2048 + col0);
      b0[nn][1] = *(const i32x4*)(Bb + nn*2048 + col1);
    }
    STAGE_A(s+1, 0);
    __builtin_amdgcn_s_barrier();
    asm volatile("s_waitcnt lgkmcnt(0)" ::: "memory");
    __builtin_amdgcn_s_setprio(1);
    #pragma unroll
    for (int m = 0; m < 4; ++m)
      #pragma unroll
      for (int nn = 0; nn < 2; ++nn) {
        acc[m][nn] = __builtin_amdgcn_mfma_i32_16x16x64_i8(a0[m][0], b0[nn][0], acc[m][nn], 0,0,0);
        acc[m][nn] = __builtin_amdgcn_mfma_i32_16x16x64_i8(a0[m][1], b0[nn][1], acc[m][nn], 0,0,0);
      }
    __builtin_amdgcn_s_setprio(0);
    __builtin_amdgcn_s_barrier();

    // ---- phase 2: read b1(n2-3); stage A1(s+1); MFMA m0-3 x n2-3 (a0 live)
    #pragma unroll
    for (int nn = 0; nn < 2; ++nn) {
      b1[nn][0] = *(const i32x4*)(Bb + 4096 + nn*2048 + col0);
      b1[nn][1] = *(const i32x4*)(Bb + 4096 + nn*2048 + col1);
    }
    STAGE_A(s+1, 1);
    __builtin_amdgcn_s_barrier();
    asm volatile("s_waitcnt lgkmcnt(0)" ::: "memory");
    __builtin_amdgcn_s_setprio(1);
    #pragma unroll
    for (int m = 0; m < 4; ++m)
      #pragma unroll
      for (int nn = 0; nn < 2; ++nn) {
        acc[m][nn+2] = __builtin_amdgcn_mfma_i32_16x16x64_i8(a0[m][0], b1[nn][0], acc[m][nn+2], 0,0,0);
        acc[m][nn+2] = __builtin_amdgcn_mfma_i32_16x16x64_i8(a0[m][1], b1[nn][1], acc[m][nn+2], 0,0,0);
      }
    __builtin_amdgcn_s_setprio(0);
    __builtin_amdgcn_s_barrier();

    // ---- phase 3: read a1(m4-7); stage B0(s+2); MFMA m4-7 x n2-3 (b1 live)
    #pragma unroll
    for (int m = 0; m < 4; ++m) {
      a1[m][0] = *(const i32x4*)(Ab + 8192 + m*2048 + col0);
      a1[m][1] = *(const i32x4*)(Ab + 8192 + m*2048 + col1);
    }
    STAGE_B(s+2, 0);
    __builtin_amdgcn_s_barrier();
    asm volatile("s_waitcnt lgkmcnt(0)" ::: "memory");
    __builtin_amdgcn_s_setprio(1);
    #pragma unroll
    for (int m = 0; m < 4; ++m)
      #pragma unroll
      for (int nn = 0; nn < 2; ++nn) {
        acc[m+4][nn+2] = __builtin_amdgcn_mfma_i32_16x16x64_i8(a1[m][0], b1[nn][0], acc[m+4][nn+2], 0,0,0);
        acc[m+4][nn+2] = __builtin_amdgcn_mfma_i32_16x16x64_i8(a1[m][1], b1[nn][1], acc[m+4][nn+2], 0,0,0);
      }
    __builtin_amdgcn_s_setprio(0);
    __builtin_amdgcn_s_barrier();

    // ---- phase 4: stage B1(s+2); vmcnt(4); MFMA m4-7 x n0-1 (a1,b0 live)
    STAGE_B(s+2, 1);
    __builtin_amdgcn_s_barrier();
    asm volatile("s_waitcnt vmcnt(4)" ::: "memory");
    __builtin_amdgcn_s_setprio(1);
    #pragma unroll
    for (int m = 0; m < 4; ++m)
      #pragma unroll
      for (int nn = 0; nn < 2; ++nn) {
        acc[m+4][nn] = __builtin_amdgcn_mfma_i32_16x16x64_i8(a1[m][0], b0[nn][0], acc[m+4][nn], 0,0,0);
        acc[m+4][nn] = __builtin_amdgcn_mfma_i32_16x16x64_i8(a1[m][1], b0[nn][1], acc[m+4][nn], 0,0,0);
      }
    __builtin_amdgcn_s_setprio(0);
    __builtin_amdgcn_s_barrier();
  }

  // epilogue: co = wm*128 + m*16 + (ln>>4)*4 + r ; pos = wn*64 + nn*16 + (ln&15)
  int coB = wm*128 + (ln >> 4) * 4;
  float iv[8][4];
  #pragma unroll
  for (int m = 0; m < 8; ++m)
    #pragma unroll
    for (int r = 0; r < 4; ++r)
      iv[m][r] = invs[coB + m*16 + r];
  int y = y0 + wn;
  size_t obase0 = (size_t)n_img * COUT * (HH*WW) + (size_t)(y - 1) * WW;
  #pragma unroll
  for (int nn = 0; nn < 4; ++nn) {
    int xx = nn*16 + (ln & 15);
    if (xx < 1 || xx > WW) continue;
    size_t ob = obase0 + (xx - 1);
    #pragma unroll
    for (int m = 0; m < 8; ++m) {
      int co = coB + m*16;
      #pragma unroll
      for (int r = 0; r < 4; ++r)
        out[ob + (size_t)(co + r) * (HH*WW)] = fmaxf((float)acc[m][nn][r] * iv[m][r], 0.0f);
    }
  }
}

extern "C" void kernel_launch(void* const* d_in, const int* in_sizes, int n_in,
                              void* d_out, int out_size, void* d_ws, size_t ws_size,
                              hipStream_t stream) {
  const float* x     = (const float*)d_in[0];
  const float* gamma = (const float*)d_in[1];
  const float* beta  = (const float*)d_in[2];
  const float* W     = (const float*)d_in[3];
  float* out = (float*)d_out;

  char* ws = (char*)d_ws;
  // layout: part [262144] | prm [8192] | invs [1024] | Wb i8 [589824] | pad | xb i8 @1MiB
  double*  part = (double*)ws;
  double*  prm  = (double*)(ws + 262144);
  float*   invs = (float*)(ws + 270336);
  int8_t*  Wb   = (int8_t*)(ws + 271360);
  int8_t*  xbuf = (int8_t*)(ws + 1048576);
  // xb: 64*58*64*256 = 60,817,408 B (+112B tap-overhang slack within ws)

  (void)hipFuncSetAttribute((const void*)conv_gemm,
                            hipFuncAttributeMaxDynamicSharedMemorySize, 131072);

  hipLaunchKernelGGL(stats_partial, dim3(256*64), dim3(256), 0, stream, x, part);
  hipLaunchKernelGGL(stats_final,   dim3(1),      dim3(256), 0, stream, part, gamma, beta, prm);
  hipLaunchKernelGGL(binarize,      dim3(64*HP),  dim3(256), 0, stream, x, prm, xbuf);
  hipLaunchKernelGGL(wrepack,       dim3(256),    dim3(256), 0, stream, W, Wb, invs);
  hipLaunchKernelGGL(conv_gemm,     dim3(896),    dim3(512), 131072, stream, xbuf, Wb, invs, out);
}